// Round 1
// baseline (366.162 us; speedup 1.0000x reference)
//
#include <hip/hip_runtime.h>

#define N_NODES 100000
#define N_EDGES 3200000
#define CH 256

#define GRID_QK 1563     // 64 nodes/block
#define GRID_E  3125     // 4 edges/thread * 256 thr = 1024 edges/block, exact cover
#define GRID_POOL 512
#define YCOPY 16

// ---- ws layout (float offsets) ----
#define OFF_TOTAL 0
#define OFF_YU16  16       // 4096 floats
#define OFF_Q     4112     // 100000
#define OFF_K     104112   // 100000
#define OFF_AWU   204112   // 100000
// end = 304112 floats ~= 1.2 MiB

// q[n]=x[n,:].Wq+bq, k[n]=x[n,:].Wk+bk. 16-lane dot groups, 4 shuffle levels.
// Also zeroes yu16 (blocks 0..15), awu, totalp for the later atomic kernels.
__global__ __launch_bounds__(256) void k_qk(const float* __restrict__ x,
                                            const float* __restrict__ Wq,
                                            const float* __restrict__ bq,
                                            const float* __restrict__ Wk,
                                            const float* __restrict__ bk,
                                            float* __restrict__ q,
                                            float* __restrict__ k,
                                            float* __restrict__ yu16,
                                            float* __restrict__ awu,
                                            float* __restrict__ totalp) {
    int t = threadIdx.x;
    int gid = blockIdx.x * 256 + t;
    if (blockIdx.x < 16) yu16[blockIdx.x * 256 + t] = 0.0f;  // zero for k_pool atomics
    if (gid < N_NODES) awu[gid] = 0.0f;                      // zero for k_edge atomics
    if (gid == 0) totalp[0] = 0.0f;
    int w = t >> 6, lane = t & 63;
    int g = lane >> 4, seg = lane & 15;
    float4 wq4[4], wk4[4];
    #pragma unroll
    for (int j = 0; j < 4; ++j) {
        wq4[j] = ((const float4*)Wq)[seg + 16 * j];
        wk4[j] = ((const float4*)Wk)[seg + 16 * j];
    }
    float bqs = bq[0], bks = bk[0];
    int base = blockIdx.x * 64 + w * 16 + g;
    #pragma unroll
    for (int i = 0; i < 4; ++i) {
        int n = base + i * 4;
        if (n < N_NODES) {
            const float4* xr = (const float4*)(x + (size_t)n * CH);
            float dq = 0.0f, dk = 0.0f;
            #pragma unroll
            for (int j = 0; j < 4; ++j) {
                float4 xv = xr[seg + 16 * j];
                dq = fmaf(xv.x, wq4[j].x, fmaf(xv.y, wq4[j].y,
                     fmaf(xv.z, wq4[j].z, fmaf(xv.w, wq4[j].w, dq))));
                dk = fmaf(xv.x, wk4[j].x, fmaf(xv.y, wk4[j].y,
                     fmaf(xv.z, wk4[j].z, fmaf(xv.w, wk4[j].w, dk))));
            }
            dq += __shfl_down(dq, 8); dq += __shfl_down(dq, 4);
            dq += __shfl_down(dq, 2); dq += __shfl_down(dq, 1);
            dk += __shfl_down(dk, 8); dk += __shfl_down(dk, 4);
            dk += __shfl_down(dk, 2); dk += __shfl_down(dk, 1);
            if (seg == 0) { q[n] = dq + bqs; k[n] = dk + bks; }
        }
    }
}

// One pass over edges: gather q[r],k[c] (L2-resident 400KB arrays), leaky+exp,
// hardware float atomic into awu[r], block-reduced atomic into totalp.
// Replaces k_sort + k_agg + k_fold (and their 38 MB of ex/row round-trip traffic).
__global__ __launch_bounds__(256) void k_edge(const int* __restrict__ ei,
                                              const float* __restrict__ q,
                                              const float* __restrict__ k,
                                              float* __restrict__ awu,
                                              float* __restrict__ totalp) {
    int t = threadIdx.x;
    int i0 = (blockIdx.x * 256 + t) * 4;                 // exact: 3125*256*4 == N_EDGES
    const int4 r4 = *(const int4*)(ei + i0);
    const int4 c4 = *(const int4*)(ei + N_EDGES + i0);
    float q0 = q[r4.x], q1 = q[r4.y], q2 = q[r4.z], q3 = q[r4.w];
    float k0 = k[c4.x], k1 = k[c4.y], k2 = k[c4.z], k3 = k[c4.w];
    float v0 = q0 * k0, v1 = q1 * k1, v2 = q2 * k2, v3 = q3 * k3;
    v0 = (v0 >= 0.0f) ? v0 : 0.2f * v0;
    v1 = (v1 >= 0.0f) ? v1 : 0.2f * v1;
    v2 = (v2 >= 0.0f) ? v2 : 0.2f * v2;
    v3 = (v3 >= 0.0f) ? v3 : 0.2f * v3;
    float e0 = __expf(v0), e1 = __expf(v1), e2 = __expf(v2), e3 = __expf(v3);
    unsafeAtomicAdd(&awu[r4.x], e0);   // global_atomic_add_f32, no CAS loop
    unsafeAtomicAdd(&awu[r4.y], e1);
    unsafeAtomicAdd(&awu[r4.z], e2);
    unsafeAtomicAdd(&awu[r4.w], e3);
    float ts = (e0 + e1) + (e2 + e3);
    #pragma unroll
    for (int off = 32; off; off >>= 1) ts += __shfl_down(ts, off);
    __shared__ float sm[4];
    if ((t & 63) == 0) sm[t >> 6] = ts;
    __syncthreads();
    if (t == 0) unsafeAtomicAdd(totalp, (sm[0] + sm[1]) + (sm[2] + sm[3]));
}

// weighted pool: yu16 atomic partials of sum_n awu[n]*x[n,:]; aw_out = awu/total
__global__ __launch_bounds__(256) void k_pool(const float* __restrict__ x,
                                              const float* __restrict__ awu,
                                              const float* __restrict__ totalp,
                                              float* __restrict__ yu16,
                                              float* __restrict__ aw_out) {
    int t = threadIdx.x, s = t >> 6, g = t & 63;
    float inv = 1.0f / totalp[0];

    const float4* X4 = (const float4*)x;
    float4 acc = make_float4(0.f, 0.f, 0.f, 0.f);
    for (int base = blockIdx.x * 8; base < N_NODES; base += GRID_POOL * 8) {
        float a0 = awu[base + s];
        float a1 = awu[base + 4 + s];
        float4 x0 = X4[(size_t)(base + s) * 64 + g];
        float4 x1 = X4[(size_t)(base + 4 + s) * 64 + g];
        acc.x = fmaf(a0, x0.x, acc.x); acc.y = fmaf(a0, x0.y, acc.y);
        acc.z = fmaf(a0, x0.z, acc.z); acc.w = fmaf(a0, x0.w, acc.w);
        acc.x = fmaf(a1, x1.x, acc.x); acc.y = fmaf(a1, x1.y, acc.y);
        acc.z = fmaf(a1, x1.z, acc.z); acc.w = fmaf(a1, x1.w, acc.w);
    }
    __shared__ float4 tmp4[4][64];
    tmp4[s][g] = acc;
    __syncthreads();
    const float* tmp = (const float*)tmp4;
    float sum = tmp[0 * 256 + t] + tmp[1 * 256 + t] + tmp[2 * 256 + t] + tmp[3 * 256 + t];
    unsafeAtomicAdd(&yu16[(blockIdx.x & (YCOPY - 1)) * 256 + t], sum);
    for (int i = blockIdx.x * 256 + t; i < N_NODES; i += GRID_POOL * 256)
        aw_out[i] = awu[i] * inv;
}

// grid 8: block j -> out[j*32 .. j*32+32)
__global__ __launch_bounds__(256) void k_final(const float* __restrict__ yu16,
                                               const float* __restrict__ totalp,
                                               const float* __restrict__ Wv,
                                               const float* __restrict__ bv,
                                               float* __restrict__ out) {
    __shared__ float ysh[256];
    __shared__ float red[256];
    int t = threadIdx.x;
    float inv = 1.0f / totalp[0];
    float yv = 0.0f;
    #pragma unroll
    for (int j = 0; j < YCOPY; ++j) yv += yu16[j * 256 + t];
    ysh[t] = yv * inv;
    __syncthreads();
    int c = blockIdx.x * 32 + (t & 31), rg = t >> 5;
    float acc = 0.0f;
    #pragma unroll
    for (int j = 0; j < 32; ++j) {
        int kk = rg * 32 + j;
        acc = fmaf(ysh[kk], Wv[(size_t)kk * CH + c], acc);
    }
    red[t] = acc;
    __syncthreads();
    if (t < 32) {
        float sv = 0.0f;
        #pragma unroll
        for (int j = 0; j < 8; ++j) sv += red[j * 32 + t];
        out[blockIdx.x * 32 + t] = sv + bv[blockIdx.x * 32 + t];
    }
}

extern "C" void kernel_launch(void* const* d_in, const int* in_sizes, int n_in,
                              void* d_out, int out_size, void* d_ws, size_t ws_size,
                              hipStream_t stream) {
    const float* x  = (const float*)d_in[0];
    const int*   ei = (const int*)d_in[1];
    const float* Wq = (const float*)d_in[2];
    const float* bq = (const float*)d_in[3];
    const float* Wk = (const float*)d_in[4];
    const float* bk = (const float*)d_in[5];
    const float* Wv = (const float*)d_in[6];
    const float* bv = (const float*)d_in[7];
    float* out = (float*)d_out;
    float* ws  = (float*)d_ws;

    float* totalp = ws + OFF_TOTAL;
    float* yu16   = ws + OFF_YU16;
    float* q      = ws + OFF_Q;
    float* k      = ws + OFF_K;
    float* awu    = ws + OFF_AWU;

    hipLaunchKernelGGL(k_qk, dim3(GRID_QK), dim3(256), 0, stream,
                       x, Wq, bq, Wk, bk, q, k, yu16, awu, totalp);
    hipLaunchKernelGGL(k_edge, dim3(GRID_E), dim3(256), 0, stream,
                       ei, q, k, awu, totalp);
    hipLaunchKernelGGL(k_pool, dim3(GRID_POOL), dim3(256), 0, stream,
                       x, awu, totalp, yu16, out + CH);
    hipLaunchKernelGGL(k_final, dim3(8), dim3(256), 0, stream,
                       yu16, totalp, Wv, bv, out);
}

// Round 3
// 260.856 us; speedup vs baseline: 1.4037x; 1.4037x over previous
//
#include <hip/hip_runtime.h>

#define N_NODES 100000
#define N_EDGES 3200000
#define CH 256

#define GRID_QK 1563     // 64 nodes/block
#define GRID_POOL 512
#define YCOPY 16

// segmented-sum geometry: 8 node-ranges x 64 edge-slices, LDS-accumulated
#define NR 8
#define RANGE 12500      // nodes per range; LDS acc = 50 KB -> 2 blocks/CU, static-safe
#define SL 64            // edge slices
#define EPS 50000        // edges per slice = N_EDGES / SL (exact)
#define HEPS 25000       // half-slice, for 2-way ILP
#define GP 391           // ceil(N_NODES/256) fold blocks -> ptot entries

// ---- ws layout (float offsets) ----
#define OFF_TOTAL 0
#define OFF_PTOT  16       // 512 (only GP=391 used)
#define OFF_YU16  528      // 4096
#define OFF_Q     4624     // 100000
#define OFF_K     104624   // 100000
#define OFF_AWU   204624   // 100000
#define OFF_PART  304624   // NR*SL*RANGE = 6,400,000 floats (25.6 MB)
// end = 6,704,624 floats ~= 26.8 MiB (ws known >= 28 MiB)

// q[n]=x[n,:].Wq+bq, k[n]=x[n,:].Wk+bk. 16-lane dot groups, 4 shuffle levels.
__global__ __launch_bounds__(256) void k_qk(const float* __restrict__ x,
                                            const float* __restrict__ Wq,
                                            const float* __restrict__ bq,
                                            const float* __restrict__ Wk,
                                            const float* __restrict__ bk,
                                            float* __restrict__ q,
                                            float* __restrict__ k,
                                            float* __restrict__ yu16) {
    int t = threadIdx.x;
    if (blockIdx.x < 16) yu16[blockIdx.x * 256 + t] = 0.0f;  // zero for k_pool atomics
    int w = t >> 6, lane = t & 63;
    int g = lane >> 4, seg = lane & 15;
    float4 wq4[4], wk4[4];
    #pragma unroll
    for (int j = 0; j < 4; ++j) {
        wq4[j] = ((const float4*)Wq)[seg + 16 * j];
        wk4[j] = ((const float4*)Wk)[seg + 16 * j];
    }
    float bqs = bq[0], bks = bk[0];
    int base = blockIdx.x * 64 + w * 16 + g;
    #pragma unroll
    for (int i = 0; i < 4; ++i) {
        int n = base + i * 4;
        if (n < N_NODES) {
            const float4* xr = (const float4*)(x + (size_t)n * CH);
            float dq = 0.0f, dk = 0.0f;
            #pragma unroll
            for (int j = 0; j < 4; ++j) {
                float4 xv = xr[seg + 16 * j];
                dq = fmaf(xv.x, wq4[j].x, fmaf(xv.y, wq4[j].y,
                     fmaf(xv.z, wq4[j].z, fmaf(xv.w, wq4[j].w, dq))));
                dk = fmaf(xv.x, wk4[j].x, fmaf(xv.y, wk4[j].y,
                     fmaf(xv.z, wk4[j].z, fmaf(xv.w, wk4[j].w, dk))));
            }
            dq += __shfl_down(dq, 8); dq += __shfl_down(dq, 4);
            dq += __shfl_down(dq, 2); dq += __shfl_down(dq, 1);
            dk += __shfl_down(dk, 8); dk += __shfl_down(dk, 4);
            dk += __shfl_down(dk, 2); dk += __shfl_down(dk, 1);
            if (seg == 0) { q[n] = dq + bqs; k[n] = dk + bks; }
        }
    }
}

// Segmented sum, stage 1: block (slice s, range r) scans slice edges; for rows in
// [r*RANGE, (r+1)*RANGE) gathers q/k (L2-resident), leaky+exp, ds_add_f32 into a
// dense 50KB LDS accumulator; writes one dense partial slab. NO global atomics.
// ei re-reads (8x nominal) are L3-absorbed (25.6 MB unique << 256 MB L3).
__global__ __launch_bounds__(1024) void k_acc(const int* __restrict__ ei,
                                              const float* __restrict__ q,
                                              const float* __restrict__ k,
                                              float* __restrict__ partial) {
    __shared__ float acc[RANGE];   // 50 KB static LDS (<= 64 KB limit)
    int t = threadIdx.x;
    int s = blockIdx.x >> 3, r = blockIdx.x & 7;
    for (int i = t; i < RANGE; i += 1024) acc[i] = 0.0f;
    __syncthreads();
    int r0 = r * RANGE;
    int e0 = s * EPS;
    // 2-way ILP: two independent gather/exp chains per iteration
    for (int i = e0 + t; i < e0 + HEPS; i += 1024) {
        int rowA = ei[i];
        int rowB = ei[i + HEPS];
        unsigned offA = (unsigned)(rowA - r0);
        unsigned offB = (unsigned)(rowB - r0);
        if (offA < RANGE) {
            int col = ei[N_EDGES + i];
            float v = q[rowA] * k[col];
            v = (v >= 0.0f) ? v : 0.2f * v;
            atomicAdd(&acc[offA], __expf(v));   // ds_add_f32
        }
        if (offB < RANGE) {
            int col = ei[N_EDGES + i + HEPS];
            float v = q[rowB] * k[col];
            v = (v >= 0.0f) ? v : 0.2f * v;
            atomicAdd(&acc[offB], __expf(v));
        }
    }
    __syncthreads();
    float* dst = partial + ((size_t)r * SL + s) * RANGE;
    for (int i = t; i < RANGE; i += 1024) dst[i] = acc[i];
}

// Stage 2: awu[n] = sum_s partial[range(n)][s][n%RANGE]; ptot[blk] = block total partial
__global__ __launch_bounds__(256) void k_fold(const float* __restrict__ partial,
                                              float* __restrict__ awu,
                                              float* __restrict__ ptot) {
    int t = threadIdx.x;
    int n = blockIdx.x * 256 + t;
    float s = 0.0f;
    if (n < N_NODES) {
        int r = n / RANGE, off = n % RANGE;   // magic-mul div
        const float* p = partial + (size_t)r * SL * RANGE + off;
        #pragma unroll 8
        for (int g = 0; g < SL; ++g) s += p[(size_t)g * RANGE];
        awu[n] = s;
    }
    float rsum = s;
    #pragma unroll
    for (int off = 32; off; off >>= 1) rsum += __shfl_down(rsum, off);
    __shared__ float sm[4];
    if ((t & 63) == 0) sm[t >> 6] = rsum;
    __syncthreads();
    if (t == 0) ptot[blockIdx.x] = sm[0] + sm[1] + sm[2] + sm[3];
}

// total inline from ptot; yu16 atomic partials; aw_out = awu/total
__global__ __launch_bounds__(256) void k_pool(const float* __restrict__ x,
                                              const float* __restrict__ awu,
                                              const float* __restrict__ ptot,
                                              float* __restrict__ totalp,
                                              float* __restrict__ yu16,
                                              float* __restrict__ aw_out) {
    int t = threadIdx.x, s = t >> 6, g = t & 63;
    // reduce ptot[0..GP) -> total (every block, cheap)
    float ts = ptot[t] + ((t + 256 < GP) ? ptot[t + 256] : 0.0f);
    #pragma unroll
    for (int off = 32; off; off >>= 1) ts += __shfl_down(ts, off);
    __shared__ float sm[4];
    __shared__ float tot;
    if (g == 0) sm[s] = ts;
    __syncthreads();
    if (t == 0) {
        tot = sm[0] + sm[1] + sm[2] + sm[3];
        if (blockIdx.x == 0) totalp[0] = tot;
    }
    __syncthreads();
    float inv = 1.0f / tot;

    const float4* X4 = (const float4*)x;
    float4 acc = make_float4(0.f, 0.f, 0.f, 0.f);
    for (int base = blockIdx.x * 8; base < N_NODES; base += GRID_POOL * 8) {
        float a0 = awu[base + s];
        float a1 = awu[base + 4 + s];
        float4 x0 = X4[(size_t)(base + s) * 64 + g];
        float4 x1 = X4[(size_t)(base + 4 + s) * 64 + g];
        acc.x = fmaf(a0, x0.x, acc.x); acc.y = fmaf(a0, x0.y, acc.y);
        acc.z = fmaf(a0, x0.z, acc.z); acc.w = fmaf(a0, x0.w, acc.w);
        acc.x = fmaf(a1, x1.x, acc.x); acc.y = fmaf(a1, x1.y, acc.y);
        acc.z = fmaf(a1, x1.z, acc.z); acc.w = fmaf(a1, x1.w, acc.w);
    }
    __shared__ float4 tmp4[4][64];
    tmp4[s][g] = acc;
    __syncthreads();
    const float* tmp = (const float*)tmp4;
    float sum = tmp[0 * 256 + t] + tmp[1 * 256 + t] + tmp[2 * 256 + t] + tmp[3 * 256 + t];
    atomicAdd(&yu16[(blockIdx.x & (YCOPY - 1)) * 256 + t], sum);
    for (int i = blockIdx.x * 256 + t; i < N_NODES; i += GRID_POOL * 256)
        aw_out[i] = awu[i] * inv;
}

// grid 8: block j -> out[j*32 .. j*32+32)
__global__ __launch_bounds__(256) void k_final(const float* __restrict__ yu16,
                                               const float* __restrict__ totalp,
                                               const float* __restrict__ Wv,
                                               const float* __restrict__ bv,
                                               float* __restrict__ out) {
    __shared__ float ysh[256];
    __shared__ float red[256];
    int t = threadIdx.x;
    float inv = 1.0f / totalp[0];
    float yv = 0.0f;
    #pragma unroll
    for (int j = 0; j < YCOPY; ++j) yv += yu16[j * 256 + t];
    ysh[t] = yv * inv;
    __syncthreads();
    int c = blockIdx.x * 32 + (t & 31), rg = t >> 5;
    float acc = 0.0f;
    #pragma unroll
    for (int j = 0; j < 32; ++j) {
        int kk = rg * 32 + j;
        acc = fmaf(ysh[kk], Wv[(size_t)kk * CH + c], acc);
    }
    red[t] = acc;
    __syncthreads();
    if (t < 32) {
        float sv = 0.0f;
        #pragma unroll
        for (int j = 0; j < 8; ++j) sv += red[j * 32 + t];
        out[blockIdx.x * 32 + t] = sv + bv[blockIdx.x * 32 + t];
    }
}

extern "C" void kernel_launch(void* const* d_in, const int* in_sizes, int n_in,
                              void* d_out, int out_size, void* d_ws, size_t ws_size,
                              hipStream_t stream) {
    const float* x  = (const float*)d_in[0];
    const int*   ei = (const int*)d_in[1];
    const float* Wq = (const float*)d_in[2];
    const float* bq = (const float*)d_in[3];
    const float* Wk = (const float*)d_in[4];
    const float* bk = (const float*)d_in[5];
    const float* Wv = (const float*)d_in[6];
    const float* bv = (const float*)d_in[7];
    float* out = (float*)d_out;
    float* ws  = (float*)d_ws;

    float* totalp  = ws + OFF_TOTAL;
    float* ptot    = ws + OFF_PTOT;
    float* yu16    = ws + OFF_YU16;
    float* q       = ws + OFF_Q;
    float* k       = ws + OFF_K;
    float* awu     = ws + OFF_AWU;
    float* partial = ws + OFF_PART;

    hipLaunchKernelGGL(k_qk, dim3(GRID_QK), dim3(256), 0, stream,
                       x, Wq, bq, Wk, bk, q, k, yu16);
    hipLaunchKernelGGL(k_acc, dim3(NR * SL), dim3(1024), 0, stream,
                       ei, q, k, partial);
    hipLaunchKernelGGL(k_fold, dim3(GP), dim3(256), 0, stream,
                       partial, awu, ptot);
    hipLaunchKernelGGL(k_pool, dim3(GRID_POOL), dim3(256), 0, stream,
                       x, awu, ptot, totalp, yu16, out + CH);
    hipLaunchKernelGGL(k_final, dim3(8), dim3(256), 0, stream,
                       yu16, totalp, Wv, bv, out);
}

// Round 4
// 249.241 us; speedup vs baseline: 1.4691x; 1.0466x over previous
//
#include <hip/hip_runtime.h>

#define N_NODES 100000
#define N_EDGES 3200000
#define CH 256

#define GRID_QK 1563     // 64 nodes/block
#define GRID_POOL 512
#define YCOPY 16

// segmented-sum geometry: 4 node-ranges x 64 edge-slices, dynamic-LDS accumulated
#define NR 4
#define RANGE 25000      // nodes per range; LDS acc = 100000 B (dynamic, >64KB static limit)
#define SL 64            // edge slices
#define EPS 50000        // edges per slice = N_EDGES / SL (exact)
#define QEPS 12500       // EPS/4 int4 loads per slice
#define GP 391           // ceil(N_NODES/256) fold blocks -> ptot entries

// ---- ws layout (float offsets) ----
#define OFF_TOTAL 0
#define OFF_PTOT  16       // 512 (only GP=391 used)
#define OFF_YU16  528      // 4096
#define OFF_Q     4624     // 100000
#define OFF_K     104624   // 100000
#define OFF_AWU   204624   // 100000
#define OFF_PART  304624   // NR*SL*RANGE = 6,400,000 floats (25.6 MB)
// end = 6,704,624 floats ~= 26.8 MiB (ws known >= 28 MiB)

// q[n]=x[n,:].Wq+bq, k[n]=x[n,:].Wk+bk. 16-lane dot groups, 4 shuffle levels.
__global__ __launch_bounds__(256) void k_qk(const float* __restrict__ x,
                                            const float* __restrict__ Wq,
                                            const float* __restrict__ bq,
                                            const float* __restrict__ Wk,
                                            const float* __restrict__ bk,
                                            float* __restrict__ q,
                                            float* __restrict__ k,
                                            float* __restrict__ yu16) {
    int t = threadIdx.x;
    if (blockIdx.x < 16) yu16[blockIdx.x * 256 + t] = 0.0f;  // zero for k_pool atomics
    int w = t >> 6, lane = t & 63;
    int g = lane >> 4, seg = lane & 15;
    float4 wq4[4], wk4[4];
    #pragma unroll
    for (int j = 0; j < 4; ++j) {
        wq4[j] = ((const float4*)Wq)[seg + 16 * j];
        wk4[j] = ((const float4*)Wk)[seg + 16 * j];
    }
    float bqs = bq[0], bks = bk[0];
    int base = blockIdx.x * 64 + w * 16 + g;
    #pragma unroll
    for (int i = 0; i < 4; ++i) {
        int n = base + i * 4;
        if (n < N_NODES) {
            const float4* xr = (const float4*)(x + (size_t)n * CH);
            float dq = 0.0f, dk = 0.0f;
            #pragma unroll
            for (int j = 0; j < 4; ++j) {
                float4 xv = xr[seg + 16 * j];
                dq = fmaf(xv.x, wq4[j].x, fmaf(xv.y, wq4[j].y,
                     fmaf(xv.z, wq4[j].z, fmaf(xv.w, wq4[j].w, dq))));
                dk = fmaf(xv.x, wk4[j].x, fmaf(xv.y, wk4[j].y,
                     fmaf(xv.z, wk4[j].z, fmaf(xv.w, wk4[j].w, dk))));
            }
            dq += __shfl_down(dq, 8); dq += __shfl_down(dq, 4);
            dq += __shfl_down(dq, 2); dq += __shfl_down(dq, 1);
            dk += __shfl_down(dk, 8); dk += __shfl_down(dk, 4);
            dk += __shfl_down(dk, 2); dk += __shfl_down(dk, 1);
            if (seg == 0) { q[n] = dq + bqs; k[n] = dk + bks; }
        }
    }
}

// Segmented sum, stage 1: block (slice s, range r) scans slice rows as int4; for
// rows in [r*RANGE,(r+1)*RANGE) gathers q/k (L2-resident), leaky+exp, ds_add_f32
// into a dense 100KB dynamic-LDS accumulator; writes one dense partial slab.
// NR=4 (vs 8) halves the redundant row-rescan L2-fill traffic; grid=256 = 1/CU.
__global__ __launch_bounds__(1024) void k_acc(const int* __restrict__ ei,
                                              const float* __restrict__ q,
                                              const float* __restrict__ k,
                                              float* __restrict__ partial) {
    extern __shared__ float acc[];   // RANGE floats = 100000 B dynamic LDS
    int t = threadIdx.x;
    int s = blockIdx.x >> 2, r = blockIdx.x & 3;
    for (int i = t; i < RANGE; i += 1024) acc[i] = 0.0f;
    __syncthreads();
    int r0 = r * RANGE;
    const int4* rows4 = (const int4*)ei;
    int q0 = s * QEPS;
    for (int i4 = q0 + t; i4 < q0 + QEPS; i4 += 1024) {
        int4 rw = rows4[i4];
        int eb = 4 * i4;
        unsigned o0 = (unsigned)(rw.x - r0);
        unsigned o1 = (unsigned)(rw.y - r0);
        unsigned o2 = (unsigned)(rw.z - r0);
        unsigned o3 = (unsigned)(rw.w - r0);
        if (o0 < RANGE) {
            float v = q[rw.x] * k[ei[N_EDGES + eb]];
            atomicAdd(&acc[o0], __expf(fmaxf(v, 0.2f * v)));   // ds_add_f32
        }
        if (o1 < RANGE) {
            float v = q[rw.y] * k[ei[N_EDGES + eb + 1]];
            atomicAdd(&acc[o1], __expf(fmaxf(v, 0.2f * v)));
        }
        if (o2 < RANGE) {
            float v = q[rw.z] * k[ei[N_EDGES + eb + 2]];
            atomicAdd(&acc[o2], __expf(fmaxf(v, 0.2f * v)));
        }
        if (o3 < RANGE) {
            float v = q[rw.w] * k[ei[N_EDGES + eb + 3]];
            atomicAdd(&acc[o3], __expf(fmaxf(v, 0.2f * v)));
        }
    }
    __syncthreads();
    float* dst = partial + ((size_t)r * SL + s) * RANGE;
    for (int i = t; i < RANGE; i += 1024) dst[i] = acc[i];
}

// Stage 2: awu[n] = sum_s partial[range(n)][s][n%RANGE]; ptot[blk] = block total partial
__global__ __launch_bounds__(256) void k_fold(const float* __restrict__ partial,
                                              float* __restrict__ awu,
                                              float* __restrict__ ptot) {
    int t = threadIdx.x;
    int n = blockIdx.x * 256 + t;
    float s = 0.0f;
    if (n < N_NODES) {
        int r = n / RANGE, off = n % RANGE;   // magic-mul div
        const float* p = partial + (size_t)r * SL * RANGE + off;
        #pragma unroll 8
        for (int g = 0; g < SL; ++g) s += p[(size_t)g * RANGE];
        awu[n] = s;
    }
    float rsum = s;
    #pragma unroll
    for (int off = 32; off; off >>= 1) rsum += __shfl_down(rsum, off);
    __shared__ float sm[4];
    if ((t & 63) == 0) sm[t >> 6] = rsum;
    __syncthreads();
    if (t == 0) ptot[blockIdx.x] = sm[0] + sm[1] + sm[2] + sm[3];
}

// total inline from ptot; yu16 atomic partials; aw_out = awu/total
__global__ __launch_bounds__(256) void k_pool(const float* __restrict__ x,
                                              const float* __restrict__ awu,
                                              const float* __restrict__ ptot,
                                              float* __restrict__ totalp,
                                              float* __restrict__ yu16,
                                              float* __restrict__ aw_out) {
    int t = threadIdx.x, s = t >> 6, g = t & 63;
    // reduce ptot[0..GP) -> total (every block, cheap)
    float ts = ptot[t] + ((t + 256 < GP) ? ptot[t + 256] : 0.0f);
    #pragma unroll
    for (int off = 32; off; off >>= 1) ts += __shfl_down(ts, off);
    __shared__ float sm[4];
    __shared__ float tot;
    if (g == 0) sm[s] = ts;
    __syncthreads();
    if (t == 0) {
        tot = sm[0] + sm[1] + sm[2] + sm[3];
        if (blockIdx.x == 0) totalp[0] = tot;
    }
    __syncthreads();
    float inv = 1.0f / tot;

    const float4* X4 = (const float4*)x;
    float4 acc = make_float4(0.f, 0.f, 0.f, 0.f);
    for (int base = blockIdx.x * 8; base < N_NODES; base += GRID_POOL * 8) {
        float a0 = awu[base + s];
        float a1 = awu[base + 4 + s];
        float4 x0 = X4[(size_t)(base + s) * 64 + g];
        float4 x1 = X4[(size_t)(base + 4 + s) * 64 + g];
        acc.x = fmaf(a0, x0.x, acc.x); acc.y = fmaf(a0, x0.y, acc.y);
        acc.z = fmaf(a0, x0.z, acc.z); acc.w = fmaf(a0, x0.w, acc.w);
        acc.x = fmaf(a1, x1.x, acc.x); acc.y = fmaf(a1, x1.y, acc.y);
        acc.z = fmaf(a1, x1.z, acc.z); acc.w = fmaf(a1, x1.w, acc.w);
    }
    __shared__ float4 tmp4[4][64];
    tmp4[s][g] = acc;
    __syncthreads();
    const float* tmp = (const float*)tmp4;
    float sum = tmp[0 * 256 + t] + tmp[1 * 256 + t] + tmp[2 * 256 + t] + tmp[3 * 256 + t];
    atomicAdd(&yu16[(blockIdx.x & (YCOPY - 1)) * 256 + t], sum);
    for (int i = blockIdx.x * 256 + t; i < N_NODES; i += GRID_POOL * 256)
        aw_out[i] = awu[i] * inv;
}

// grid 8: block j -> out[j*32 .. j*32+32)
__global__ __launch_bounds__(256) void k_final(const float* __restrict__ yu16,
                                               const float* __restrict__ totalp,
                                               const float* __restrict__ Wv,
                                               const float* __restrict__ bv,
                                               float* __restrict__ out) {
    __shared__ float ysh[256];
    __shared__ float red[256];
    int t = threadIdx.x;
    float inv = 1.0f / totalp[0];
    float yv = 0.0f;
    #pragma unroll
    for (int j = 0; j < YCOPY; ++j) yv += yu16[j * 256 + t];
    ysh[t] = yv * inv;
    __syncthreads();
    int c = blockIdx.x * 32 + (t & 31), rg = t >> 5;
    float acc = 0.0f;
    #pragma unroll
    for (int j = 0; j < 32; ++j) {
        int kk = rg * 32 + j;
        acc = fmaf(ysh[kk], Wv[(size_t)kk * CH + c], acc);
    }
    red[t] = acc;
    __syncthreads();
    if (t < 32) {
        float sv = 0.0f;
        #pragma unroll
        for (int j = 0; j < 8; ++j) sv += red[j * 32 + t];
        out[blockIdx.x * 32 + t] = sv + bv[blockIdx.x * 32 + t];
    }
}

extern "C" void kernel_launch(void* const* d_in, const int* in_sizes, int n_in,
                              void* d_out, int out_size, void* d_ws, size_t ws_size,
                              hipStream_t stream) {
    const float* x  = (const float*)d_in[0];
    const int*   ei = (const int*)d_in[1];
    const float* Wq = (const float*)d_in[2];
    const float* bq = (const float*)d_in[3];
    const float* Wk = (const float*)d_in[4];
    const float* bk = (const float*)d_in[5];
    const float* Wv = (const float*)d_in[6];
    const float* bv = (const float*)d_in[7];
    float* out = (float*)d_out;
    float* ws  = (float*)d_ws;

    float* totalp  = ws + OFF_TOTAL;
    float* ptot    = ws + OFF_PTOT;
    float* yu16    = ws + OFF_YU16;
    float* q       = ws + OFF_Q;
    float* k       = ws + OFF_K;
    float* awu     = ws + OFF_AWU;
    float* partial = ws + OFF_PART;

    // allow 100 KB dynamic LDS for k_acc (one-time host-side attribute; not a stream op)
    static bool lds_init = false;
    if (!lds_init) {
        (void)hipFuncSetAttribute((const void*)k_acc,
                                  hipFuncAttributeMaxDynamicSharedMemorySize,
                                  RANGE * 4);
        lds_init = true;
    }

    hipLaunchKernelGGL(k_qk, dim3(GRID_QK), dim3(256), 0, stream,
                       x, Wq, bq, Wk, bk, q, k, yu16);
    hipLaunchKernelGGL(k_acc, dim3(NR * SL), dim3(1024), RANGE * 4, stream,
                       ei, q, k, partial);
    hipLaunchKernelGGL(k_fold, dim3(GP), dim3(256), 0, stream,
                       partial, awu, ptot);
    hipLaunchKernelGGL(k_pool, dim3(GRID_POOL), dim3(256), 0, stream,
                       x, awu, ptot, totalp, yu16, out + CH);
    hipLaunchKernelGGL(k_final, dim3(8), dim3(256), 0, stream,
                       yu16, totalp, Wv, bv, out);
}